// Round 2
// baseline (1821.665 us; speedup 1.0000x reference)
//
#include <hip/hip_runtime.h>
#include <stdint.h>

// RouteCapsule: I=1024, D=64, O=32, E=64, B=64, 3 routing iters.
// u[o,i,b,e] = sum_d x*w materialized once (fp16, 256 MB) via bf16 MFMA.
// Round-2 changes (latency hiding):
//  - u_gemm: register double-buffer of global loads + LDS double-buffer
//    (1 barrier/i, loads for i+1 in flight during MFMA/store of i)
//  - logits: explicit 2-deep pipeline over o; squash folded in (reads raw s,
//    computes scale per row via 4-lane shfl) -> no vbuf, no squash kernels
//  - sweight: 2048 blocks, fully unrolled 16-i inner loop, hoisted c loads

#define IC 1024
#define OC 32
#define DD 64
#define EE 64
#define BB 64

typedef __attribute__((ext_vector_type(8))) short short8;
typedef __attribute__((ext_vector_type(16))) float f32x16;
typedef _Float16 half8 __attribute__((ext_vector_type(8)));

__device__ __forceinline__ unsigned short f2bf(float f) {
    unsigned int u = __float_as_uint(f);
    u = (u + 0x7FFFu + ((u >> 16) & 1u)) >> 16;   // RNE
    return (unsigned short)u;
}
__device__ __forceinline__ unsigned int pk2(float a, float b) {
    return (unsigned int)f2bf(a) | ((unsigned int)f2bf(b) << 16);
}

// ---------------------------------------------------------------------------
// u_gemm: u[o,i,b,e] + s0 = (1/32) sum_i u.  grid (chunk=32, o=32), 256 thr.
// Register-dbuf global loads, LDS-dbuf staging, 1 syncthreads per i.
// ---------------------------------------------------------------------------
__global__ __launch_bounds__(256)
void u_gemm_kernel(const float* __restrict__ x,
                   const float* __restrict__ w,
                   _Float16* __restrict__ u,
                   float* __restrict__ s_out)
{
    __shared__ unsigned short xs[2][64 * 68];   // [b][d] bf16
    __shared__ unsigned short wT[2][64 * 68];   // [e][d] bf16
    const int t = threadIdx.x;
    const int o = blockIdx.y;
    const int chunk = blockIdx.x;
    const int lane = t & 63;
    const int wv = t >> 6;
    const int bh = wv & 1, eh = wv >> 1;
    const int seg = t & 7;
    const int rrow = t >> 3;
    const int d0 = rrow * 2;
    const int ar = bh * 32 + (lane & 31);
    const int br = eh * 32 + (lane & 31);

    f32x16 stot = (f32x16)0.0f;

#define LOADSET(i_, X0,X1,X2,X3, W0,W1,W2,W3) do {                          \
    const float* xp = x + (((size_t)(i_)) * BB + rrow) * DD + seg * 8;      \
    X0 = *(const float4*)xp;            X1 = *(const float4*)(xp + 4);      \
    X2 = *(const float4*)(xp + 32*DD);  X3 = *(const float4*)(xp + 32*DD+4);\
    const float* wp = w + ((((size_t)o) * IC + (i_)) * DD + d0) * EE + seg*8;\
    W0 = *(const float4*)wp;            W1 = *(const float4*)(wp + 4);      \
    W2 = *(const float4*)(wp + EE);     W3 = *(const float4*)(wp + EE + 4); \
} while(0)

#define STAGESET(bf_, X0,X1,X2,X3, W0,W1,W2,W3) do {                        \
    uint2* dx0 = (uint2*)&xs[bf_][rrow * 68 + seg * 8];                     \
    dx0[0] = make_uint2(pk2(X0.x, X0.y), pk2(X0.z, X0.w));                  \
    dx0[1] = make_uint2(pk2(X1.x, X1.y), pk2(X1.z, X1.w));                  \
    uint2* dx1 = (uint2*)&xs[bf_][(rrow + 32) * 68 + seg * 8];              \
    dx1[0] = make_uint2(pk2(X2.x, X2.y), pk2(X2.z, X2.w));                  \
    dx1[1] = make_uint2(pk2(X3.x, X3.y), pk2(X3.z, X3.w));                  \
    const float r0_[8] = {W0.x,W0.y,W0.z,W0.w,W1.x,W1.y,W1.z,W1.w};         \
    const float r1_[8] = {W2.x,W2.y,W2.z,W2.w,W3.x,W3.y,W3.z,W3.w};         \
    _Pragma("unroll")                                                       \
    for (int j = 0; j < 8; ++j)                                             \
        *(unsigned int*)&wT[bf_][(seg * 8 + j) * 68 + d0] = pk2(r0_[j], r1_[j]); \
} while(0)

#define MFMA_STORE(bf_, i_) do {                                            \
    f32x16 acc = (f32x16)0.0f;                                              \
    _Pragma("unroll")                                                       \
    for (int kk = 0; kk < 4; ++kk) {                                        \
        const int k0 = kk * 16 + (lane >> 5) * 8;                           \
        uint2 alo = *(const uint2*)&xs[bf_][ar * 68 + k0];                  \
        uint2 ahi = *(const uint2*)&xs[bf_][ar * 68 + k0 + 4];              \
        uint2 blo = *(const uint2*)&wT[bf_][br * 68 + k0];                  \
        uint2 bhi = *(const uint2*)&wT[bf_][br * 68 + k0 + 4];              \
        union { uint4 q; short8 s; } au, bu;                                \
        au.q = make_uint4(alo.x, alo.y, ahi.x, ahi.y);                      \
        bu.q = make_uint4(blo.x, blo.y, bhi.x, bhi.y);                      \
        acc = __builtin_amdgcn_mfma_f32_32x32x16_bf16(au.s, bu.s, acc, 0, 0, 0); \
    }                                                                       \
    _Float16* ubp = u + ((((size_t)o) * IC + (i_)) * BB) * EE;              \
    _Pragma("unroll")                                                       \
    for (int r = 0; r < 16; ++r) {                                          \
        const int gb = bh * 32 + (r & 3) + 8 * (r >> 2) + 4 * (lane >> 5);  \
        const int ge = eh * 32 + (lane & 31);                               \
        ubp[gb * EE + ge] = (_Float16)acc[r];                               \
        stot[r] += acc[r];                                                  \
    }                                                                       \
} while(0)

    float4 XA0,XA1,XA2,XA3, WA0,WA1,WA2,WA3;
    float4 XB0,XB1,XB2,XB3, WB0,WB1,WB2,WB3;
    const int i0 = chunk * 32;
    LOADSET(i0, XA0,XA1,XA2,XA3, WA0,WA1,WA2,WA3);
    for (int ii = 0; ii < 32; ii += 2) {
        STAGESET(0, XA0,XA1,XA2,XA3, WA0,WA1,WA2,WA3);
        LOADSET(i0 + ii + 1, XB0,XB1,XB2,XB3, WB0,WB1,WB2,WB3);
        __syncthreads();
        MFMA_STORE(0, i0 + ii);
        STAGESET(1, XB0,XB1,XB2,XB3, WB0,WB1,WB2,WB3);
        if (ii + 2 < 32)
            LOADSET(i0 + ii + 2, XA0,XA1,XA2,XA3, WA0,WA1,WA2,WA3);
        __syncthreads();
        MFMA_STORE(1, i0 + ii + 1);
    }
    #pragma unroll
    for (int r = 0; r < 16; ++r) {
        const int gb = bh * 32 + (r & 3) + 8 * (r >> 2) + 4 * (lane >> 5);
        const int ge = eh * 32 + (lane & 31);
        atomicAdd(&s_out[(((size_t)o) * BB + gb) * EE + ge], stot[r] * (1.0f / 32.0f));
    }
#undef LOADSET
#undef STAGESET
#undef MFMA_STORE
}

// ---------------------------------------------------------------------------
// logits (squash folded in): per i, L[o,b] = scale_o(b) * sum_e u*s (+bprev),
// softmax over o -> c.  s is the RAW pre-squash accumulator; scale computed
// per (o,row) from |s|^2 via 4-lane shfl.  2-deep pipeline over o.
// ---------------------------------------------------------------------------
template<bool FIRST>
__global__ __launch_bounds__(256)
void logits_kernel(const _Float16* __restrict__ u,
                   const float* __restrict__ s,       // [O][B][E] fp32 raw
                   const float* __restrict__ bprev,   // [O][I][B]
                   float* __restrict__ bout,          // [O][I][B]
                   float* __restrict__ cbuf)          // [O][I][B]
{
    __shared__ float Lp[OC][BB];
    const int t = threadIdx.x;
    const int i = blockIdx.x;
    const int b = t >> 2;
    const int eq = t & 3;
    const size_t OSU = (size_t)IC * BB * EE;   // u o-stride (elements)
    const _Float16* up = u + (((size_t)i) * BB + b) * EE + eq * 16;
    const float*    sp = s + ((size_t)b) * EE + eq * 16;

    half8 uA0, uA1, uB0, uB1;
    float4 sA0, sA1, sA2, sA3, sB0, sB1, sB2, sB3;

    auto ldA = [&](int o) {
        const _Float16* p = up + (size_t)o * OSU;
        uA0 = *(const half8*)p; uA1 = *(const half8*)(p + 8);
        const float* q = sp + (size_t)o * (BB * EE);
        sA0 = *(const float4*)q;      sA1 = *(const float4*)(q + 4);
        sA2 = *(const float4*)(q + 8); sA3 = *(const float4*)(q + 12);
    };
    auto ldB = [&](int o) {
        const _Float16* p = up + (size_t)o * OSU;
        uB0 = *(const half8*)p; uB1 = *(const half8*)(p + 8);
        const float* q = sp + (size_t)o * (BB * EE);
        sB0 = *(const float4*)q;      sB1 = *(const float4*)(q + 4);
        sB2 = *(const float4*)(q + 8); sB3 = *(const float4*)(q + 12);
    };
    auto body = [&](half8 u0, half8 u1, float4 v0, float4 v1, float4 v2,
                    float4 v3, int o) {
        float sq = v0.x*v0.x + v0.y*v0.y + v0.z*v0.z + v0.w*v0.w
                 + v1.x*v1.x + v1.y*v1.y + v1.z*v1.z + v1.w*v1.w
                 + v2.x*v2.x + v2.y*v2.y + v2.z*v2.z + v2.w*v2.w
                 + v3.x*v3.x + v3.y*v3.y + v3.z*v3.z + v3.w*v3.w;
        sq += __shfl_xor(sq, 1);
        sq += __shfl_xor(sq, 2);
        const float scale = sqrtf(sq) / (1.0f + sq);
        float p = (float)u0[0]*v0.x + (float)u0[1]*v0.y + (float)u0[2]*v0.z + (float)u0[3]*v0.w
                + (float)u0[4]*v1.x + (float)u0[5]*v1.y + (float)u0[6]*v1.z + (float)u0[7]*v1.w
                + (float)u1[0]*v2.x + (float)u1[1]*v2.y + (float)u1[2]*v2.z + (float)u1[3]*v2.w
                + (float)u1[4]*v3.x + (float)u1[5]*v3.y + (float)u1[6]*v3.z + (float)u1[7]*v3.w;
        p *= scale;
        p += __shfl_xor(p, 1);
        p += __shfl_xor(p, 2);
        if (eq == 0) Lp[o][b] = p;
    };

    ldA(0);
    for (int o = 0; o < OC; o += 2) {
        ldB(o + 1);
        body(uA0, uA1, sA0, sA1, sA2, sA3, o);
        if (o + 2 < OC) ldA(o + 2);
        body(uB0, uB1, sB0, sB1, sB2, sB3, o + 1);
    }
    __syncthreads();
    if (t < BB) {                              // softmax over o, one thread per b
        const int bb = t;
        float lt[OC];
        float m = -1e30f;
        #pragma unroll
        for (int o = 0; o < OC; ++o) {
            float L = Lp[o][bb];
            if (!FIRST) L += bprev[(((size_t)o) * IC + i) * BB + bb];
            if (FIRST)  bout[(((size_t)o) * IC + i) * BB + bb] = L;
            lt[o] = L;
            m = fmaxf(m, L);
        }
        float Z = 0.f;
        #pragma unroll
        for (int o = 0; o < OC; ++o) { lt[o] = __expf(lt[o] - m); Z += lt[o]; }
        const float rZ = 1.0f / Z;
        #pragma unroll
        for (int o = 0; o < OC; ++o)
            cbuf[(((size_t)o) * IC + i) * BB + bb] = lt[o] * rZ;
    }
}

// ---------------------------------------------------------------------------
// s[o,b,e] += sum_i c[o,i,b]*u[o,i,b,e].  grid (chunk=64 of 16 i, o=32).
// Fully unrolled; c loads hoisted; 2048 blocks -> 32 waves/CU.
// ---------------------------------------------------------------------------
__global__ __launch_bounds__(256)
void sweight_kernel(const _Float16* __restrict__ u,
                    const float* __restrict__ cbuf,
                    float* __restrict__ s_out)
{
    const int t = threadIdx.x;
    const int chunk = blockIdx.x;
    const int o = blockIdx.y;
    const int b = t >> 2;
    const int eq = t & 3;
    const int i0 = chunk * 16;

    float c[16];
    #pragma unroll
    for (int j = 0; j < 16; ++j)
        c[j] = cbuf[(((size_t)o) * IC + i0 + j) * BB + b];

    float acc[16];
    #pragma unroll
    for (int j = 0; j < 16; ++j) acc[j] = 0.f;

    const _Float16* up = u + ((((size_t)o) * IC + i0) * BB + b) * EE + eq * 16;
    #pragma unroll
    for (int ii = 0; ii < 16; ++ii) {
        const half8 u0 = *(const half8*)(up + (size_t)ii * (BB * EE));
        const half8 u1 = *(const half8*)(up + (size_t)ii * (BB * EE) + 8);
        #pragma unroll
        for (int j = 0; j < 8; ++j) acc[j]     += c[ii] * (float)u0[j];
        #pragma unroll
        for (int j = 0; j < 8; ++j) acc[8 + j] += c[ii] * (float)u1[j];
    }
    float* sp = s_out + (((size_t)o) * BB + b) * EE + eq * 16;
    #pragma unroll
    for (int j = 0; j < 16; ++j) atomicAdd(&sp[j], acc[j]);
}

// final: out = squash(s2)
__global__ __launch_bounds__(256)
void squash_kernel(const float* __restrict__ s, float* __restrict__ vout)
{
    const int o = blockIdx.x;
    const int lane = threadIdx.x & 63;
    const int wv = threadIdx.x >> 6;
    for (int b = wv; b < BB; b += 4) {
        const size_t idx = (((size_t)o) * BB + b) * EE + lane;
        const float val = s[idx];
        float sq = val * val;
        #pragma unroll
        for (int off = 1; off < 64; off <<= 1)
            sq += __shfl_xor(sq, off);
        const float r = sqrtf(sq);
        vout[idx] = val * (r / (1.0f + sq));
    }
}

extern "C" void kernel_launch(void* const* d_in, const int* in_sizes, int n_in,
                              void* d_out, int out_size, void* d_ws, size_t ws_size,
                              hipStream_t stream)
{
    const float* x = (const float*)d_in[0];   // [I][B][D] fp32
    const float* w = (const float*)d_in[1];   // [O][I][D][E] fp32
    float* out = (float*)d_out;               // [O][B][E] fp32

    char* ws = (char*)d_ws;
    float*    s_buf = (float*)ws;                            // 512 KB
    float*    b1    = (float*)(ws + (1 << 20));              // 8 MB
    float*    cbuf  = (float*)(ws + (1 << 20) + (8 << 20));  // 8 MB
    _Float16* u     = (_Float16*)(ws + (17u << 20));         // 256 MB

    const dim3 blk(256);

    // u = x.w (one pass over route_w); s0 = (1/32) sum_i u fused in
    hipMemsetAsync(s_buf, 0, 1 << 19, stream);
    u_gemm_kernel<<<dim3(32, 32), blk, 0, stream>>>(x, w, u, s_buf);
    // iter 1: v0 = squash(s0) inline; b1 = u.v0; c1 = softmax_o(b1)
    logits_kernel<true><<<1024, blk, 0, stream>>>(u, s_buf, nullptr, b1, cbuf);
    hipMemsetAsync(s_buf, 0, 1 << 19, stream);
    sweight_kernel<<<dim3(64, 32), blk, 0, stream>>>(u, cbuf, s_buf);
    // iter 2: v1 = squash(s1) inline; b2 = b1 + u.v1; c2 = softmax_o(b2)
    logits_kernel<false><<<1024, blk, 0, stream>>>(u, s_buf, b1, nullptr, cbuf);
    hipMemsetAsync(s_buf, 0, 1 << 19, stream);
    sweight_kernel<<<dim3(64, 32), blk, 0, stream>>>(u, cbuf, s_buf);
    // out = squash(s2)
    squash_kernel<<<32, blk, 0, stream>>>(s_buf, out);
}

// Round 3
// 1174.847 us; speedup vs baseline: 1.5506x; 1.5506x over previous
//
#include <hip/hip_runtime.h>
#include <stdint.h>

// RouteCapsule: I=1024, D=64, O=32, E=64, B=64, 3 routing iters.
// u[o,i,b,e] = sum_d x*w materialized once (fp16, 256 MB) via bf16 MFMA.
// Round-3 changes:
//  - NO atomics anywhere: per-block [64][64] partial tiles -> part[o][chunk]
//    buffer (16 MB), folded by a tiny reduce kernel. (Round-2 counters showed
//    8.4M device-scope atomicAdds = 268 MB of HBM-side RMW = ~370 us drain.)
//  - sweight/logits: explicit 4-deep rotating register prefetch (constant
//    slot indices after full unroll), launch_bounds(256,4) so the pipeline
//    actually owns VGPRs (round-2 compiled to 32 VGPRs and serialized).
//  - no memsets needed (partials fully overwritten each pass).

#define IC 1024
#define OC 32
#define DD 64
#define EE 64
#define BB 64
#define NCH 32          // i-chunks for partial buffers

typedef __attribute__((ext_vector_type(8))) short short8;
typedef __attribute__((ext_vector_type(16))) float f32x16;
typedef _Float16 half8 __attribute__((ext_vector_type(8)));

__device__ __forceinline__ unsigned short f2bf(float f) {
    unsigned int u = __float_as_uint(f);
    u = (u + 0x7FFFu + ((u >> 16) & 1u)) >> 16;   // RNE
    return (unsigned short)u;
}
__device__ __forceinline__ unsigned int pk2(float a, float b) {
    return (unsigned int)f2bf(a) | ((unsigned int)f2bf(b) << 16);
}

// ---------------------------------------------------------------------------
// u_gemm: u[o,i,b,e] = sum_d x*w  (bf16 MFMA), partial s0 tile -> part.
// grid (chunk=32, o=32), 256 thr. Register-dbuf global loads, LDS-dbuf.
// ---------------------------------------------------------------------------
__global__ __launch_bounds__(256)
void u_gemm_kernel(const float* __restrict__ x,
                   const float* __restrict__ w,
                   _Float16* __restrict__ u,
                   float* __restrict__ part)   // [O][NCH][B][E]
{
    __shared__ unsigned short xs[2][64 * 68];   // [b][d] bf16
    __shared__ unsigned short wT[2][64 * 68];   // [e][d] bf16
    const int t = threadIdx.x;
    const int o = blockIdx.y;
    const int chunk = blockIdx.x;
    const int lane = t & 63;
    const int wv = t >> 6;
    const int bh = wv & 1, eh = wv >> 1;
    const int seg = t & 7;
    const int rrow = t >> 3;
    const int d0 = rrow * 2;
    const int ar = bh * 32 + (lane & 31);
    const int br = eh * 32 + (lane & 31);

    f32x16 stot = (f32x16)0.0f;

#define LOADSET(i_, X0,X1,X2,X3, W0,W1,W2,W3) do {                          \
    const float* xp = x + (((size_t)(i_)) * BB + rrow) * DD + seg * 8;      \
    X0 = *(const float4*)xp;            X1 = *(const float4*)(xp + 4);      \
    X2 = *(const float4*)(xp + 32*DD);  X3 = *(const float4*)(xp + 32*DD+4);\
    const float* wp = w + ((((size_t)o) * IC + (i_)) * DD + d0) * EE + seg*8;\
    W0 = *(const float4*)wp;            W1 = *(const float4*)(wp + 4);      \
    W2 = *(const float4*)(wp + EE);     W3 = *(const float4*)(wp + EE + 4); \
} while(0)

#define STAGESET(bf_, X0,X1,X2,X3, W0,W1,W2,W3) do {                        \
    uint2* dx0 = (uint2*)&xs[bf_][rrow * 68 + seg * 8];                     \
    dx0[0] = make_uint2(pk2(X0.x, X0.y), pk2(X0.z, X0.w));                  \
    dx0[1] = make_uint2(pk2(X1.x, X1.y), pk2(X1.z, X1.w));                  \
    uint2* dx1 = (uint2*)&xs[bf_][(rrow + 32) * 68 + seg * 8];              \
    dx1[0] = make_uint2(pk2(X2.x, X2.y), pk2(X2.z, X2.w));                  \
    dx1[1] = make_uint2(pk2(X3.x, X3.y), pk2(X3.z, X3.w));                  \
    const float r0_[8] = {W0.x,W0.y,W0.z,W0.w,W1.x,W1.y,W1.z,W1.w};         \
    const float r1_[8] = {W2.x,W2.y,W2.z,W2.w,W3.x,W3.y,W3.z,W3.w};         \
    _Pragma("unroll")                                                       \
    for (int j = 0; j < 8; ++j)                                             \
        *(unsigned int*)&wT[bf_][(seg * 8 + j) * 68 + d0] = pk2(r0_[j], r1_[j]); \
} while(0)

#define MFMA_STORE(bf_, i_) do {                                            \
    f32x16 acc = (f32x16)0.0f;                                              \
    _Pragma("unroll")                                                       \
    for (int kk = 0; kk < 4; ++kk) {                                        \
        const int k0 = kk * 16 + (lane >> 5) * 8;                           \
        uint2 alo = *(const uint2*)&xs[bf_][ar * 68 + k0];                  \
        uint2 ahi = *(const uint2*)&xs[bf_][ar * 68 + k0 + 4];              \
        uint2 blo = *(const uint2*)&wT[bf_][br * 68 + k0];                  \
        uint2 bhi = *(const uint2*)&wT[bf_][br * 68 + k0 + 4];              \
        union { uint4 q; short8 s; } au, bu;                                \
        au.q = make_uint4(alo.x, alo.y, ahi.x, ahi.y);                      \
        bu.q = make_uint4(blo.x, blo.y, bhi.x, bhi.y);                      \
        acc = __builtin_amdgcn_mfma_f32_32x32x16_bf16(au.s, bu.s, acc, 0, 0, 0); \
    }                                                                       \
    _Float16* ubp = u + ((((size_t)o) * IC + (i_)) * BB) * EE;              \
    _Pragma("unroll")                                                       \
    for (int r = 0; r < 16; ++r) {                                          \
        const int gb = bh * 32 + (r & 3) + 8 * (r >> 2) + 4 * (lane >> 5);  \
        const int ge = eh * 32 + (lane & 31);                               \
        ubp[gb * EE + ge] = (_Float16)acc[r];                               \
        stot[r] += acc[r];                                                  \
    }                                                                       \
} while(0)

    float4 XA0,XA1,XA2,XA3, WA0,WA1,WA2,WA3;
    float4 XB0,XB1,XB2,XB3, WB0,WB1,WB2,WB3;
    const int i0 = chunk * 32;
    LOADSET(i0, XA0,XA1,XA2,XA3, WA0,WA1,WA2,WA3);
    for (int ii = 0; ii < 32; ii += 2) {
        STAGESET(0, XA0,XA1,XA2,XA3, WA0,WA1,WA2,WA3);
        LOADSET(i0 + ii + 1, XB0,XB1,XB2,XB3, WB0,WB1,WB2,WB3);
        __syncthreads();
        MFMA_STORE(0, i0 + ii);
        STAGESET(1, XB0,XB1,XB2,XB3, WB0,WB1,WB2,WB3);
        if (ii + 2 < 32)
            LOADSET(i0 + ii + 2, XA0,XA1,XA2,XA3, WA0,WA1,WA2,WA3);
        __syncthreads();
        MFMA_STORE(1, i0 + ii + 1);
    }
    float* pp = part + ((((size_t)o) * NCH + chunk) * BB) * EE;
    #pragma unroll
    for (int r = 0; r < 16; ++r) {
        const int gb = bh * 32 + (r & 3) + 8 * (r >> 2) + 4 * (lane >> 5);
        const int ge = eh * 32 + (lane & 31);
        pp[gb * EE + ge] = stot[r];
    }
#undef LOADSET
#undef STAGESET
#undef MFMA_STORE
}

// ---------------------------------------------------------------------------
// reduce: s[o,b,e] = scale * sum_ch part[o,ch,b,e].  16 MB read, 512 KB write.
// grid 128 x 256 thr, one float4 per thread.
// ---------------------------------------------------------------------------
__global__ __launch_bounds__(256)
void reduce_part_kernel(const float* __restrict__ part,
                        float* __restrict__ s, const float scale)
{
    const int gid = blockIdx.x * 256 + threadIdx.x;   // 32768 float4 slots
    const int o = gid >> 10;
    const int r = (gid & 1023) * 4;
    const float* pp = part + (((size_t)o) * NCH) * (BB * EE) + r;
    float4 a0 = make_float4(0.f, 0.f, 0.f, 0.f);
    float4 a1 = make_float4(0.f, 0.f, 0.f, 0.f);
    #pragma unroll
    for (int ch = 0; ch < NCH; ch += 2) {
        const float4 v0 = *(const float4*)(pp + (size_t)ch * (BB * EE));
        const float4 v1 = *(const float4*)(pp + (size_t)(ch + 1) * (BB * EE));
        a0.x += v0.x; a0.y += v0.y; a0.z += v0.z; a0.w += v0.w;
        a1.x += v1.x; a1.y += v1.y; a1.z += v1.z; a1.w += v1.w;
    }
    float4 rr;
    rr.x = (a0.x + a1.x) * scale; rr.y = (a0.y + a1.y) * scale;
    rr.z = (a0.z + a1.z) * scale; rr.w = (a0.w + a1.w) * scale;
    *(float4*)(s + ((size_t)o) * (BB * EE) + r) = rr;
}

// ---------------------------------------------------------------------------
// logits (squash folded in): per i, L[o,b] = scale_o(b) * sum_e u*s (+bprev),
// softmax over o -> c.  4-deep u prefetch (HBM), 2-deep s prefetch (L2-hot).
// ---------------------------------------------------------------------------
template<bool FIRST>
__global__ __launch_bounds__(256, 4)
void logits_kernel(const _Float16* __restrict__ u,
                   const float* __restrict__ s,       // [O][B][E] fp32 raw
                   const float* __restrict__ bprev,   // [O][I][B]
                   float* __restrict__ bout,          // [O][I][B]
                   float* __restrict__ cbuf)          // [O][I][B]
{
    __shared__ float Lp[OC][BB];
    const int t = threadIdx.x;
    const int i = blockIdx.x;
    const int b = t >> 2;
    const int eq = t & 3;
    const size_t OSU = (size_t)IC * BB * EE;   // u o-stride (elements)
    const _Float16* up = u + (((size_t)i) * BB + b) * EE + eq * 16;
    const float*    sp = s + ((size_t)b) * EE + eq * 16;

    half8 pu0[4], pu1[4];
    float4 ps0[2], ps1[2], ps2[2], ps3[2];

    #pragma unroll
    for (int k = 0; k < 4; ++k) {
        const _Float16* p = up + (size_t)k * OSU;
        pu0[k] = *(const half8*)p; pu1[k] = *(const half8*)(p + 8);
    }
    #pragma unroll
    for (int k = 0; k < 2; ++k) {
        const float* q = sp + (size_t)k * (BB * EE);
        ps0[k] = *(const float4*)q;       ps1[k] = *(const float4*)(q + 4);
        ps2[k] = *(const float4*)(q + 8); ps3[k] = *(const float4*)(q + 12);
    }

    #pragma unroll
    for (int o = 0; o < OC; ++o) {
        const int us = o & 3, ss = o & 1;
        const half8 u0 = pu0[us], u1 = pu1[us];
        const float4 v0 = ps0[ss], v1 = ps1[ss], v2 = ps2[ss], v3 = ps3[ss];
        if (o + 4 < OC) {
            const _Float16* p = up + (size_t)(o + 4) * OSU;
            pu0[us] = *(const half8*)p; pu1[us] = *(const half8*)(p + 8);
        }
        if (o + 2 < OC) {
            const float* q = sp + (size_t)(o + 2) * (BB * EE);
            ps0[ss] = *(const float4*)q;       ps1[ss] = *(const float4*)(q + 4);
            ps2[ss] = *(const float4*)(q + 8); ps3[ss] = *(const float4*)(q + 12);
        }
        float sq = v0.x*v0.x + v0.y*v0.y + v0.z*v0.z + v0.w*v0.w
                 + v1.x*v1.x + v1.y*v1.y + v1.z*v1.z + v1.w*v1.w
                 + v2.x*v2.x + v2.y*v2.y + v2.z*v2.z + v2.w*v2.w
                 + v3.x*v3.x + v3.y*v3.y + v3.z*v3.z + v3.w*v3.w;
        sq += __shfl_xor(sq, 1);
        sq += __shfl_xor(sq, 2);
        const float scale = sqrtf(sq) / (1.0f + sq);
        float p = (float)u0[0]*v0.x + (float)u0[1]*v0.y + (float)u0[2]*v0.z + (float)u0[3]*v0.w
                + (float)u0[4]*v1.x + (float)u0[5]*v1.y + (float)u0[6]*v1.z + (float)u0[7]*v1.w
                + (float)u1[0]*v2.x + (float)u1[1]*v2.y + (float)u1[2]*v2.z + (float)u1[3]*v2.w
                + (float)u1[4]*v3.x + (float)u1[5]*v3.y + (float)u1[6]*v3.z + (float)u1[7]*v3.w;
        p *= scale;
        p += __shfl_xor(p, 1);
        p += __shfl_xor(p, 2);
        if (eq == 0) Lp[o][b] = p;
    }
    __syncthreads();
    if (t < BB) {                              // softmax over o, one thread per b
        const int bb = t;
        float lt[OC];
        float m = -1e30f;
        #pragma unroll
        for (int o = 0; o < OC; ++o) {
            float L = Lp[o][bb];
            if (!FIRST) L += bprev[(((size_t)o) * IC + i) * BB + bb];
            if (FIRST)  bout[(((size_t)o) * IC + i) * BB + bb] = L;
            lt[o] = L;
            m = fmaxf(m, L);
        }
        float Z = 0.f;
        #pragma unroll
        for (int o = 0; o < OC; ++o) { lt[o] = __expf(lt[o] - m); Z += lt[o]; }
        const float rZ = 1.0f / Z;
        #pragma unroll
        for (int o = 0; o < OC; ++o)
            cbuf[(((size_t)o) * IC + i) * BB + bb] = lt[o] * rZ;
    }
}

// ---------------------------------------------------------------------------
// sweight: part[o,chunk,b,e] = sum_{i in chunk} c[o,i,b]*u[o,i,b,e].
// grid (chunk=32, o=32); 4-deep rotating prefetch; plain stores (no atomics).
// ---------------------------------------------------------------------------
__global__ __launch_bounds__(256, 4)
void sweight_kernel(const _Float16* __restrict__ u,
                    const float* __restrict__ cbuf,
                    float* __restrict__ part)   // [O][NCH][B][E]
{
    const int t = threadIdx.x;
    const int chunk = blockIdx.x;
    const int o = blockIdx.y;
    const int b = t >> 2;
    const int eq = t & 3;
    const int i0 = chunk * 32;

    const _Float16* up = u + ((((size_t)o) * IC + i0) * BB + b) * EE + eq * 16;
    const float*    cp = cbuf + (((size_t)o) * IC + i0) * BB + b;

    half8 pu0[4], pu1[4];
    float pc[4];
    #pragma unroll
    for (int k = 0; k < 4; ++k) {
        const _Float16* p = up + (size_t)k * (BB * EE);
        pu0[k] = *(const half8*)p;
        pu1[k] = *(const half8*)(p + 8);
        pc[k]  = cp[k * BB];
    }
    float acc[16];
    #pragma unroll
    for (int j = 0; j < 16; ++j) acc[j] = 0.f;

    #pragma unroll
    for (int ii = 0; ii < 32; ++ii) {
        const int sl = ii & 3;
        const half8 u0 = pu0[sl];
        const half8 u1 = pu1[sl];
        const float c  = pc[sl];
        if (ii + 4 < 32) {
            const _Float16* p = up + (size_t)(ii + 4) * (BB * EE);
            pu0[sl] = *(const half8*)p;
            pu1[sl] = *(const half8*)(p + 8);
            pc[sl]  = cp[(ii + 4) * BB];
        }
        #pragma unroll
        for (int j = 0; j < 8; ++j) acc[j]     += c * (float)u0[j];
        #pragma unroll
        for (int j = 0; j < 8; ++j) acc[8 + j] += c * (float)u1[j];
    }
    float* pp = part + ((((size_t)o) * NCH + chunk) * BB + b) * EE + eq * 16;
    *(float4*)(pp +  0) = make_float4(acc[0],  acc[1],  acc[2],  acc[3]);
    *(float4*)(pp +  4) = make_float4(acc[4],  acc[5],  acc[6],  acc[7]);
    *(float4*)(pp +  8) = make_float4(acc[8],  acc[9],  acc[10], acc[11]);
    *(float4*)(pp + 12) = make_float4(acc[12], acc[13], acc[14], acc[15]);
}

// final: out = squash(s2)
__global__ __launch_bounds__(256)
void squash_kernel(const float* __restrict__ s, float* __restrict__ vout)
{
    const int o = blockIdx.x;
    const int lane = threadIdx.x & 63;
    const int wv = threadIdx.x >> 6;
    for (int b = wv; b < BB; b += 4) {
        const size_t idx = (((size_t)o) * BB + b) * EE + lane;
        const float val = s[idx];
        float sq = val * val;
        #pragma unroll
        for (int off = 1; off < 64; off <<= 1)
            sq += __shfl_xor(sq, off);
        const float r = sqrtf(sq);
        vout[idx] = val * (r / (1.0f + sq));
    }
}

extern "C" void kernel_launch(void* const* d_in, const int* in_sizes, int n_in,
                              void* d_out, int out_size, void* d_ws, size_t ws_size,
                              hipStream_t stream)
{
    const float* x = (const float*)d_in[0];   // [I][B][D] fp32
    const float* w = (const float*)d_in[1];   // [O][I][D][E] fp32
    float* out = (float*)d_out;               // [O][B][E] fp32

    char* ws = (char*)d_ws;
    float*    s_buf = (float*)ws;                            // 512 KB
    float*    b1    = (float*)(ws + (1u << 20));             // 8 MB
    float*    cbuf  = (float*)(ws + (9u << 20));             // 8 MB
    float*    partb = (float*)(ws + (17u << 20));            // 16 MB
    _Float16* u     = (_Float16*)(ws + (33u << 20));         // 256 MB

    const dim3 blk(256);

    // u = x.w (one pass over route_w); s0 partials fused in
    u_gemm_kernel<<<dim3(32, 32), blk, 0, stream>>>(x, w, u, partb);
    reduce_part_kernel<<<128, blk, 0, stream>>>(partb, s_buf, 1.0f / 32.0f);
    // iter 1: v0 = squash(s0) inline; b1 = u.v0; c1 = softmax_o(b1)
    logits_kernel<true><<<1024, blk, 0, stream>>>(u, s_buf, nullptr, b1, cbuf);
    sweight_kernel<<<dim3(32, 32), blk, 0, stream>>>(u, cbuf, partb);
    reduce_part_kernel<<<128, blk, 0, stream>>>(partb, s_buf, 1.0f);
    // iter 2: v1 = squash(s1) inline; b2 = b1 + u.v1; c2 = softmax_o(b2)
    logits_kernel<false><<<1024, blk, 0, stream>>>(u, s_buf, b1, nullptr, cbuf);
    sweight_kernel<<<dim3(32, 32), blk, 0, stream>>>(u, cbuf, partb);
    reduce_part_kernel<<<128, blk, 0, stream>>>(partb, s_buf, 1.0f);
    // out = squash(s2)
    squash_kernel<<<32, blk, 0, stream>>>(s_buf, out);
}